// Round 6
// baseline (232.246 us; speedup 1.0000x reference)
//
#include <hip/hip_runtime.h>

typedef __attribute__((ext_vector_type(8))) short short8;
typedef __attribute__((ext_vector_type(16))) float floatx16;
typedef __attribute__((ext_vector_type(4))) float floatx4;
typedef unsigned short ushort16_t;
typedef unsigned int uint32;

#define BB 8
#define CC 384
#define NPIX 1024
#define TOTCH 176      // 64 q + 16 k + 96 v
#define BN_EPS 1e-5f

// ---------- helpers ----------
__device__ __forceinline__ ushort16_t f2bf(float x) {
    uint32 u = __float_as_uint(x);
    u += 0x7FFFu + ((u >> 16) & 1u);
    return (ushort16_t)(u >> 16);
}
__device__ __forceinline__ uint32 pk2(float a, float b) {
    uint32 ua = __float_as_uint(a); ua += 0x7FFFu + ((ua >> 16) & 1u);
    uint32 ub = __float_as_uint(b); ub += 0x7FFFu + ((ub >> 16) & 1u);
    return (ua >> 16) | (ub & 0xFFFF0000u);
}
__device__ __forceinline__ int div48(int x) {   // valid for x < 16384
    return (int)(((unsigned)x * 21846u) >> 20);
}

// ws layout (float units):
// qkv  [B][176][N]        @ 0         (1441792)
// sA   [176]              @ 1441792
// sB   [176]              @ 1441968
// ksm  [B][16][N]         @ 1442144   (131072)
// qt_g bf16 [n][kh2][bh32][8]                 @f 1573216 (262144 f)
// vt_g bf16 [b][mt32][vh2][vt3][mq4][v16][8]  @f 1835360 (393216 f)
// lc_g bf16 [b][vh2][vt3][mq4][v16][8]        @f 2228576 (12288 f)
// xbf  bf16 [col=b*1024+n][c384]              @f 2240864 (1572864 f)
// wbf  bf16 [row192][c384]                    @f 3813728 (36864 f)

// ---------------- K0: transpose x -> xbf via LDS; W -> wbf ------------------
__global__ __launch_bounds__(256) void k_xt(const float* __restrict__ x,
    const float* __restrict__ Wq, const float* __restrict__ Wk,
    const float* __restrict__ Wv,
    ushort16_t* __restrict__ xbf, ushort16_t* __restrict__ wbf)
{
    int bx = blockIdx.x, t = threadIdx.x;
    if (bx < 256) {
        __shared__ __align__(16) ushort16_t T[32 * 392];
        int col0 = bx * 32;
        int b = col0 >> 10, nbase = col0 & 1023;
        const float* xb = x + (size_t)b * (CC * NPIX) + nbase;
        #pragma unroll
        for (int j = 0; j < 12; ++j) {
            int idx = t + 256 * j;
            int c = idx >> 3, ng = idx & 7;
            float4 f = *(const float4*)(xb + (size_t)c * NPIX + ng * 4);
            int n = ng * 4;
            T[(n + 0) * 392 + c] = f2bf(f.x);
            T[(n + 1) * 392 + c] = f2bf(f.y);
            T[(n + 2) * 392 + c] = f2bf(f.z);
            T[(n + 3) * 392 + c] = f2bf(f.w);
        }
        __syncthreads();
        #pragma unroll
        for (int j = 0; j < 6; ++j) {
            int task = t + 256 * j;
            int col = div48(task);
            int ch  = task - col * 48;
            uint4 w = *(const uint4*)&T[col * 392 + ch * 8];
            *(uint4*)&xbf[(size_t)(col0 + col) * CC + ch * 8] = w;
        }
    } else {
        #pragma unroll
        for (int jj = 0; jj < 9; ++jj) {
            int idx8 = ((bx - 256) * 9 + jj) * 256 + t;
            int row = div48(idx8);
            int g   = idx8 - row * 48;
            float4 f0, f1;
            if (row < 176) {
                const float* src;
                if (row < 64)       src = Wq + (size_t)row * CC;
                else if (row < 80)  src = Wk + (size_t)(row - 64) * CC;
                else                src = Wv + (size_t)(row - 80) * CC;
                f0 = *(const float4*)(src + g * 8);
                f1 = *(const float4*)(src + g * 8 + 4);
            } else {
                f0.x = f0.y = f0.z = f0.w = 0.f;
                f1 = f0;
            }
            uint4 w;
            w.x = pk2(f0.x, f0.y); w.y = pk2(f0.z, f0.w);
            w.z = pk2(f1.x, f1.y); w.w = pk2(f1.z, f1.w);
            *(uint4*)&wbf[(size_t)row * CC + g * 8] = w;
        }
    }
}

// ---------------- K1: q/k/v projection via MFMA (no LDS) --------------------
__global__ __launch_bounds__(256) void k_proj(const ushort16_t* __restrict__ xbf,
    const ushort16_t* __restrict__ wbf, float* __restrict__ qkv)
{
    int t = threadIdx.x;
    int wave = t >> 6, lane = t & 63;
    int ct = blockIdx.x * 4 + wave;       // col tile [0,512)
    int r0 = blockIdx.y * 16;             // row base (176 = 11*16 exact)
    int col = ct * 16 + (lane & 15);
    int kh  = lane >> 4;                  // 0..3 (k-half of 8)
    const ushort16_t* ap = wbf + (size_t)(r0 + (lane & 15)) * CC + kh * 8;
    const ushort16_t* bp = xbf + (size_t)col * CC + kh * 8;
    floatx4 acc = {0.f, 0.f, 0.f, 0.f};
    short8 a0 = *(const short8*)ap;
    short8 b0 = *(const short8*)bp;
    #pragma unroll
    for (int k = 1; k < 12; ++k) {
        short8 a1 = *(const short8*)(ap + k * 32);
        short8 b1 = *(const short8*)(bp + k * 32);
        acc = __builtin_amdgcn_mfma_f32_16x16x32_bf16(a0, b0, acc, 0, 0, 0);
        a0 = a1; b0 = b1;
    }
    acc = __builtin_amdgcn_mfma_f32_16x16x32_bf16(a0, b0, acc, 0, 0, 0);
    int b = col >> 10, n = col & 1023;
    #pragma unroll
    for (int r = 0; r < 4; ++r) {
        int ch = r0 + (lane >> 4) * 4 + r;
        qkv[((size_t)b * TOTCH + ch) * NPIX + n] = acc[r];
    }
}

// ---------------- K2: BN stats + softmax (merged, float4) -------------------
__global__ __launch_bounds__(256) void k_bnsm(const float* __restrict__ qkv,
    const float* __restrict__ gq, const float* __restrict__ bq,
    const float* __restrict__ gv, const float* __restrict__ bv,
    float* __restrict__ sA, float* __restrict__ sB, float* __restrict__ ksm)
{
    int bx = blockIdx.x, tid = threadIdx.x;
    int wid = tid >> 6, lane = tid & 63;
    if (bx < 160) {
        int ch = bx;
        int row; float gamma, beta;
        if (ch < 64) { row = ch; gamma = gq[ch]; beta = bq[ch]; }
        else { int j = ch - 64; row = 80 + j; gamma = gv[j]; beta = bv[j]; }
        float s = 0.f, ss = 0.f;
        #pragma unroll
        for (int j = 0; j < 8; ++j) {
            int i4 = tid + 256 * j;
            int b = i4 >> 8, n4 = i4 & 255;
            float4 f = *(const float4*)(qkv + ((size_t)b * TOTCH + row) * NPIX
                                            + n4 * 4);
            s  += f.x + f.y + f.z + f.w;
            ss += f.x * f.x + f.y * f.y + f.z * f.z + f.w * f.w;
        }
        #pragma unroll
        for (int off = 32; off > 0; off >>= 1) {
            s  += __shfl_down(s, off);
            ss += __shfl_down(ss, off);
        }
        __shared__ float rs[4], rss[4];
        if (lane == 0) { rs[wid] = s; rss[wid] = ss; }
        __syncthreads();
        if (tid == 0) {
            float S  = rs[0] + rs[1] + rs[2] + rs[3];
            float SS = rss[0] + rss[1] + rss[2] + rss[3];
            float inv = 1.f / (BB * NPIX);
            float mean = S * inv;
            float var  = SS * inv - mean * mean;
            float a = gamma * rsqrtf(var + BN_EPS);
            sA[row] = a;
            sB[row] = beta - mean * a;
        }
    } else {
        int idx = bx - 160;
        int kc = idx & 15, b = idx >> 4;
        const float* rowp = qkv + ((size_t)b * TOTCH + 64 + kc) * NPIX;
        float4 v4 = *(const float4*)(rowp + tid * 4);
        float v[4] = {v4.x, v4.y, v4.z, v4.w};
        float mx = fmaxf(fmaxf(v[0], v[1]), fmaxf(v[2], v[3]));
        #pragma unroll
        for (int off = 32; off > 0; off >>= 1) mx = fmaxf(mx, __shfl_down(mx, off));
        __shared__ float sm[4], ssum[4];
        if (lane == 0) sm[wid] = mx;
        __syncthreads();
        mx = fmaxf(fmaxf(sm[0], sm[1]), fmaxf(sm[2], sm[3]));
        float e[4], s = 0.f;
        #pragma unroll
        for (int j = 0; j < 4; ++j) { e[j] = __expf(v[j] - mx); s += e[j]; }
        #pragma unroll
        for (int off = 32; off > 0; off >>= 1) s += __shfl_down(s, off);
        if (lane == 0) ssum[wid] = s;
        __syncthreads();
        float inv = 1.f / (ssum[0] + ssum[1] + ssum[2] + ssum[3]);
        float4 o;
        o.x = e[0] * inv; o.y = e[1] * inv; o.z = e[2] * inv; o.w = e[3] * inv;
        *(float4*)(ksm + ((size_t)b * 16 + kc) * NPIX + tid * 4) = o;
    }
}

// ---------------- K3: pack q/v (bf16 tiled) + content lambda (fused) --------
__global__ __launch_bounds__(256) void k_packlc(const float* __restrict__ qkv,
    const float* __restrict__ sA, const float* __restrict__ sB,
    const float* __restrict__ ksm,
    ushort16_t* __restrict__ qt_g, ushort16_t* __restrict__ vt_g,
    ushort16_t* __restrict__ lc_g)
{
    int bx = blockIdx.x, t = threadIdx.x;
    if (bx < 128) {
        // q part: qt_g[n][kh][bh][8]; one (n, bh) per thread
        int bh = t & 31, nn = (t >> 5) & 7;
        int n = bx * 8 + nn;
        int b = bh >> 2, h = bh & 3;
        float vals[16];
        #pragma unroll
        for (int k = 0; k < 16; ++k) {
            int ch = h * 16 + k;
            vals[k] = qkv[((size_t)b * TOTCH + ch) * NPIX + n] * sA[ch] + sB[ch];
        }
        uint4 w0, w1;
        w0.x = pk2(vals[0], vals[1]);  w0.y = pk2(vals[2], vals[3]);
        w0.z = pk2(vals[4], vals[5]);  w0.w = pk2(vals[6], vals[7]);
        w1.x = pk2(vals[8], vals[9]);  w1.y = pk2(vals[10], vals[11]);
        w1.z = pk2(vals[12], vals[13]); w1.w = pk2(vals[14], vals[15]);
        *(uint4*)&qt_g[(size_t)n * 512 + bh * 8]       = w0;
        *(uint4*)&qt_g[(size_t)n * 512 + 256 + bh * 8] = w1;
    } else if (bx < 512) {
        // v part: vt_g[b][mt][vh][vt][mq][vl][8]
        int gi = (bx - 128) * 256 + t;   // < 98304
        int m8 = gi & 127;
        int vg = (gi >> 7) % 96;
        int b  = gi / (96 * 128);
        int m  = m8 * 8;
        int row = 80 + vg;
        float a = sA[row], bb = sB[row];
        const float* p = qkv + ((size_t)b * TOTCH + row) * NPIX + m;
        float4 f0 = *(const float4*)p;
        float4 f1 = *(const float4*)(p + 4);
        uint4 w;
        w.x = pk2(f0.x * a + bb, f0.y * a + bb);
        w.y = pk2(f0.z * a + bb, f0.w * a + bb);
        w.z = pk2(f1.x * a + bb, f1.y * a + bb);
        w.w = pk2(f1.z * a + bb, f1.w * a + bb);
        int mt = m >> 5, mq = (m >> 3) & 3;
        int vhh = vg / 48, vtt = (vg % 48) >> 4, vl = vg & 15;
        size_t idx = ((((size_t)b * 32 + mt) * 2 + vhh) * 3 + vtt) * 512
                   + mq * 128 + vl * 8;
        *(uint4*)&vt_g[idx] = w;
    } else {
        // content lambda: thread t owns m in [4t, 4t+4) -> coalesced rows
        int gi = bx - 512;
        int v = gi % 96, b = gi / 96;
        int row = 80 + v;
        float a = sA[row], bb = sB[row];
        const float* vp = qkv + ((size_t)b * TOTCH + row) * NPIX;
        const float* kp = ksm + (size_t)b * 16 * NPIX;
        float4 vv = *(const float4*)(vp + t * 4);
        float4 vhat;
        vhat.x = vv.x * a + bb; vhat.y = vv.y * a + bb;
        vhat.z = vv.z * a + bb; vhat.w = vv.w * a + bb;
        float acc[16];
        #pragma unroll
        for (int k = 0; k < 16; ++k) {
            float4 kk = *(const float4*)(kp + (size_t)k * NPIX + t * 4);
            acc[k] = kk.x * vhat.x + kk.y * vhat.y
                   + kk.z * vhat.z + kk.w * vhat.w;
        }
        #pragma unroll
        for (int k = 0; k < 16; ++k) {
            #pragma unroll
            for (int off = 32; off > 0; off >>= 1)
                acc[k] += __shfl_down(acc[k], off);
        }
        __shared__ float red[16][4];
        int wid = t >> 6, lane = t & 63;
        if (lane == 0) {
            #pragma unroll
            for (int k = 0; k < 16; ++k) red[k][wid] = acc[k];
        }
        __syncthreads();
        int vhh = v / 48, vtt = (v % 48) >> 4, vl = v & 15;
        size_t plane = ((size_t)(b * 2 + vhh) * 3 + vtt) * 512;
        if (t < 16) {
            int k = t;
            float val = red[k][0] + red[k][1] + red[k][2] + red[k][3];
            lc_g[plane + (k >> 3) * 128 + vl * 8 + (k & 7)] = f2bf(val);
        } else if (t < 18) {
            int mq = 2 + (t - 16);
            uint4 z; z.x = z.y = z.z = z.w = 0u;
            *(uint4*)&lc_g[plane + mq * 128 + vl * 8] = z;
        }
    }
}

// ---------------- K4: fused MFMA position+content lambda (m-split TLP) ------
// grid (128 n0, 2 vh, 4 ms) = 1024 blocks, 512 thr. LDS = S_s only (32 KB).
// V and P(A-frag) go straight to registers, prefetched one iter ahead.
// Each ms block handles 8 m-tiles; partial outputs combined via atomicAdd
// into memset-zeroed out. Content lambda added by ms==0 blocks only.
__global__ __launch_bounds__(512, 2) void k_main(const float* __restrict__ pos,
    const ushort16_t* __restrict__ qt_g, const ushort16_t* __restrict__ vt_g,
    const ushort16_t* __restrict__ lc_g, float* __restrict__ out)
{
    __shared__ __align__(16) ushort16_t S_s[2][8192];   // 32 KB
    int tid  = threadIdx.x;
    int lane = tid & 63;
    int wave = tid >> 6;          // phase-1: n index; phase-2: b index
    int n0 = blockIdx.x * 8;
    int vh = blockIdx.y;
    int ms = blockIdx.z;          // m-split: m-tiles [ms*8, ms*8+8)

    int col1 = lane & 31, half = lane >> 5;
    int pb = col1 >> 2, ph = col1 & 3;
    int pplane = pb * 2 + (ph >> 1);
    int pf = pplane & 7;
    int pcb = ph & 1;
    int b2 = wave;

    // q fragment: fixed for whole kernel
    short8 qfr = *(const short8*)(qt_g + (size_t)(n0 + wave) * 512
                                  + half * 256 + col1 * 8);

    floatx4 acc[2][3];
    #pragma unroll
    for (int hg = 0; hg < 2; ++hg)
        #pragma unroll
        for (int vt = 0; vt < 3; ++vt)
            acc[hg][vt] = floatx4{0.f, 0.f, 0.f, 0.f};

    floatx16 z16;
    #pragma unroll
    for (int i = 0; i < 16; ++i) z16[i] = 0.f;

    // A-frag source: P[n=n0+wave][m=col1 + 32*it][k=half*8 ..], fp32
    const float* pA = pos + ((size_t)(n0 + wave) * 1024 + col1) * 16 + half * 8;
    // V source: vt_g[b2][it][vh][vt][...] + lane*8
    const ushort16_t* pV = vt_g + (size_t)b2 * 98304 + (size_t)vh * 1536
                         + lane * 8;

    int it0 = ms * 8;
    // prologue loads (iter it0)
    float4 a0 = *(const float4*)(pA + (size_t)it0 * 512);
    float4 a1 = *(const float4*)(pA + (size_t)it0 * 512 + 4);
    const ushort16_t* v0p = pV + (size_t)it0 * 3072;
    short8 av0 = *(const short8*)(v0p);
    short8 av1 = *(const short8*)(v0p + 512);
    short8 av2 = *(const short8*)(v0p + 1024);

    for (int i = 0; i < 8; ++i) {
        // prefetch next iter's A and V into registers
        float4 na0, na1;
        short8 nv0, nv1, nv2;
        if (i < 7) {
            const float* p = pA + (size_t)(it0 + i + 1) * 512;
            na0 = *(const float4*)p;
            na1 = *(const float4*)(p + 4);
            const ushort16_t* vp = pV + (size_t)(it0 + i + 1) * 3072;
            nv0 = *(const short8*)(vp);
            nv1 = *(const short8*)(vp + 512);
            nv2 = *(const short8*)(vp + 1024);
        }
        // phase-1 (n = wave): S = P * q
        {
            uint4 aw;
            aw.x = pk2(a0.x, a0.y); aw.y = pk2(a0.z, a0.w);
            aw.z = pk2(a1.x, a1.y); aw.w = pk2(a1.z, a1.w);
            short8 afr = *(short8*)&aw;
            floatx16 d = __builtin_amdgcn_mfma_f32_32x32x16_bf16(
                afr, qfr, z16, 0, 0, 0);
            int nx = wave ^ pf;
            ushort16_t* Sb = S_s[i & 1];
            #pragma unroll
            for (int q = 0; q < 4; ++q) {
                int c = q * 16 + pcb * 8 + nx;
                uint2 wv;
                wv.x = pk2(d[q * 4 + 0], d[q * 4 + 1]);
                wv.y = pk2(d[q * 4 + 2], d[q * 4 + 3]);
                *(uint2*)&Sb[pplane * 512 + c * 8 + half * 4] = wv;
            }
        }
        __syncthreads();   // one barrier per iter
        // phase-2 (b = wave): acc += V * S
        {
            const ushort16_t* Sb = S_s[i & 1];
            #pragma unroll
            for (int hg = 0; hg < 2; ++hg) {
                int p2 = b2 * 2 + hg, f2 = p2 & 7;
                short8 bs = *(const short8*)&Sb[p2 * 512
                    + ((lane >> 4) * 16 + ((lane & 15) ^ f2)) * 8];
                acc[hg][0] = __builtin_amdgcn_mfma_f32_16x16x32_bf16(
                    av0, bs, acc[hg][0], 0, 0, 0);
                acc[hg][1] = __builtin_amdgcn_mfma_f32_16x16x32_bf16(
                    av1, bs, acc[hg][1], 0, 0, 0);
                acc[hg][2] = __builtin_amdgcn_mfma_f32_16x16x32_bf16(
                    av2, bs, acc[hg][2], 0, 0, 0);
            }
        }
        if (i < 7) { a0 = na0; a1 = na1; av0 = nv0; av1 = nv1; av2 = nv2; }
    }

    // ---- content-lambda extension: ms==0 blocks only ----
    if (ms == 0) {
        const ushort16_t* lsrc = lc_g + (size_t)(b2 * 2 + vh) * 1536 + lane * 8;
        short8 lv0 = *(const short8*)(lsrc);
        short8 lv1 = *(const short8*)(lsrc + 512);
        short8 lv2 = *(const short8*)(lsrc + 1024);
        {
            // S_ext from register q fragment (same lane decode as phase-1)
            int c = half * 16 + pcb * 8 + (wave ^ pf);
            *(short8*)&S_s[0][pplane * 512 + c * 8] = qfr;
            int zp = tid >> 5, zr = tid & 31;
            int zc = (2 + (zr >> 4)) * 16 + ((zr & 15) ^ (zp & 7));
            uint4 z; z.x = z.y = z.z = z.w = 0u;
            *(uint4*)&S_s[0][zp * 512 + zc * 8] = z;
        }
        __syncthreads();
        #pragma unroll
        for (int hg = 0; hg < 2; ++hg) {
            int p2 = b2 * 2 + hg, f2 = p2 & 7;
            short8 bs = *(const short8*)&S_s[0][p2 * 512
                + ((lane >> 4) * 16 + ((lane & 15) ^ f2)) * 8];
            acc[hg][0] = __builtin_amdgcn_mfma_f32_16x16x32_bf16(
                lv0, bs, acc[hg][0], 0, 0, 0);
            acc[hg][1] = __builtin_amdgcn_mfma_f32_16x16x32_bf16(
                lv1, bs, acc[hg][1], 0, 0, 0);
            acc[hg][2] = __builtin_amdgcn_mfma_f32_16x16x32_bf16(
                lv2, bs, acc[hg][2], 0, 0, 0);
        }
    }

    // ---- epilogue: atomic accumulate into zeroed out ----
    {
        int cn = lane & 15;
        int nloc = cn & 7;
        #pragma unroll
        for (int hg = 0; hg < 2; ++hg) {
            int h = hg * 2 + (cn >> 3);
            #pragma unroll
            for (int vt = 0; vt < 3; ++vt) {
                #pragma unroll
                for (int r = 0; r < 4; ++r) {
                    int v = vh * 48 + vt * 16 + (lane >> 4) * 4 + r;
                    unsafeAtomicAdd(
                        &out[(size_t)(b2 * 384 + h * 96 + v) * 1024 + n0 + nloc],
                        acc[hg][vt][r]);
                }
            }
        }
    }
}

extern "C" void kernel_launch(void* const* d_in, const int* in_sizes, int n_in,
                              void* d_out, int out_size, void* d_ws, size_t ws_size,
                              hipStream_t stream) {
    const float* x   = (const float*)d_in[0];
    const float* Wq  = (const float*)d_in[1];
    const float* Wk  = (const float*)d_in[2];
    const float* Wv  = (const float*)d_in[3];
    const float* gq  = (const float*)d_in[4];
    const float* bq  = (const float*)d_in[5];
    const float* gv  = (const float*)d_in[6];
    const float* bv  = (const float*)d_in[7];
    const float* pos = (const float*)d_in[8];
    float* out = (float*)d_out;
    float* ws  = (float*)d_ws;

    float* qkv = ws;
    float* sA  = ws + 1441792;
    float* sB  = ws + 1441968;
    float* ksm = ws + 1442144;
    ushort16_t* qt_g = (ushort16_t*)(ws + 1573216);
    ushort16_t* vt_g = (ushort16_t*)(ws + 1835360);
    ushort16_t* lc_g = (ushort16_t*)(ws + 2228576);
    ushort16_t* xbf  = (ushort16_t*)(ws + 2240864);
    ushort16_t* wbf  = (ushort16_t*)(ws + 3813728);

    hipMemsetAsync(d_out, 0, (size_t)out_size * sizeof(float), stream);
    k_xt<<<dim3(260), dim3(256), 0, stream>>>(x, Wq, Wk, Wv, xbf, wbf);
    k_proj<<<dim3(128, 11), dim3(256), 0, stream>>>(xbf, wbf, qkv);
    k_bnsm<<<dim3(288), dim3(256), 0, stream>>>(qkv, gq, bq, gv, bv, sA, sB, ksm);
    k_packlc<<<dim3(1280), dim3(256), 0, stream>>>(qkv, sA, sB, ksm,
                                                   qt_g, vt_g, lc_g);
    k_main<<<dim3(128, 2, 4), dim3(512), 0, stream>>>(pos, qt_g, vt_g, lc_g, out);
}

// Round 7
// 179.297 us; speedup vs baseline: 1.2953x; 1.2953x over previous
//
#include <hip/hip_runtime.h>

typedef __attribute__((ext_vector_type(8))) short short8;
typedef __attribute__((ext_vector_type(16))) float floatx16;
typedef __attribute__((ext_vector_type(4))) float floatx4;
typedef unsigned short ushort16_t;
typedef unsigned int uint32;

#define BB 8
#define CC 384
#define NPIX 1024
#define TOTCH 176      // 64 q + 16 k + 96 v
#define BN_EPS 1e-5f

// ---------- helpers ----------
__device__ __forceinline__ ushort16_t f2bf(float x) {
    uint32 u = __float_as_uint(x);
    u += 0x7FFFu + ((u >> 16) & 1u);
    return (ushort16_t)(u >> 16);
}
__device__ __forceinline__ uint32 pk2(float a, float b) {
    uint32 ua = __float_as_uint(a); ua += 0x7FFFu + ((ua >> 16) & 1u);
    uint32 ub = __float_as_uint(b); ub += 0x7FFFu + ((ub >> 16) & 1u);
    return (ua >> 16) | (ub & 0xFFFF0000u);
}
__device__ __forceinline__ int div48(int x) {   // valid for x < 16384
    return (int)(((unsigned)x * 21846u) >> 20);
}
// lgkmcnt(0), vmcnt unconstrained (63), expcnt unconstrained (7)
#define LGKM0_ONLY 0xC07F

// ws layout (float units):
// qkv  [B][176][N]        @ 0         (1441792)
// sA   [176]              @ 1441792
// sB   [176]              @ 1441968
// ksm  [B][16][N]         @ 1442144   (131072)
// qt_g bf16 [n][kh2][bh32][8]                 @f 1573216 (262144 f)
// vt_g bf16 [b][mt32][vh2][vt3][mq4][v16][8]  @f 1835360 (393216 f)
// lc_g bf16 [b][vh2][vt3][mq4][v16][8]        @f 2228576 (12288 f)
// xbf  bf16 [col=b*1024+n][c384]              @f 2240864 (1572864 f)
// wbf  bf16 [row192][c384]                    @f 3813728 (36864 f)

// ---------------- K0: transpose x -> xbf via LDS; W -> wbf ------------------
__global__ __launch_bounds__(256) void k_xt(const float* __restrict__ x,
    const float* __restrict__ Wq, const float* __restrict__ Wk,
    const float* __restrict__ Wv,
    ushort16_t* __restrict__ xbf, ushort16_t* __restrict__ wbf)
{
    int bx = blockIdx.x, t = threadIdx.x;
    if (bx < 256) {
        __shared__ __align__(16) ushort16_t T[32 * 392];
        int col0 = bx * 32;
        int b = col0 >> 10, nbase = col0 & 1023;
        const float* xb = x + (size_t)b * (CC * NPIX) + nbase;
        #pragma unroll
        for (int j = 0; j < 12; ++j) {
            int idx = t + 256 * j;
            int c = idx >> 3, ng = idx & 7;
            float4 f = *(const float4*)(xb + (size_t)c * NPIX + ng * 4);
            int n = ng * 4;
            T[(n + 0) * 392 + c] = f2bf(f.x);
            T[(n + 1) * 392 + c] = f2bf(f.y);
            T[(n + 2) * 392 + c] = f2bf(f.z);
            T[(n + 3) * 392 + c] = f2bf(f.w);
        }
        __syncthreads();
        #pragma unroll
        for (int j = 0; j < 6; ++j) {
            int task = t + 256 * j;
            int col = div48(task);
            int ch  = task - col * 48;
            uint4 w = *(const uint4*)&T[col * 392 + ch * 8];
            *(uint4*)&xbf[(size_t)(col0 + col) * CC + ch * 8] = w;
        }
    } else {
        #pragma unroll
        for (int jj = 0; jj < 9; ++jj) {
            int idx8 = ((bx - 256) * 9 + jj) * 256 + t;
            int row = div48(idx8);
            int g   = idx8 - row * 48;
            float4 f0, f1;
            if (row < 176) {
                const float* src;
                if (row < 64)       src = Wq + (size_t)row * CC;
                else if (row < 80)  src = Wk + (size_t)(row - 64) * CC;
                else                src = Wv + (size_t)(row - 80) * CC;
                f0 = *(const float4*)(src + g * 8);
                f1 = *(const float4*)(src + g * 8 + 4);
            } else {
                f0.x = f0.y = f0.z = f0.w = 0.f;
                f1 = f0;
            }
            uint4 w;
            w.x = pk2(f0.x, f0.y); w.y = pk2(f0.z, f0.w);
            w.z = pk2(f1.x, f1.y); w.w = pk2(f1.z, f1.w);
            *(uint4*)&wbf[(size_t)row * CC + g * 8] = w;
        }
    }
}

// ---------------- K1: q/k/v projection via MFMA (no LDS) --------------------
__global__ __launch_bounds__(256) void k_proj(const ushort16_t* __restrict__ xbf,
    const ushort16_t* __restrict__ wbf, float* __restrict__ qkv)
{
    int t = threadIdx.x;
    int wave = t >> 6, lane = t & 63;
    int ct = blockIdx.x * 4 + wave;       // col tile [0,512)
    int r0 = blockIdx.y * 16;             // row base (176 = 11*16 exact)
    int col = ct * 16 + (lane & 15);
    int kh  = lane >> 4;                  // 0..3 (k-half of 8)
    const ushort16_t* ap = wbf + (size_t)(r0 + (lane & 15)) * CC + kh * 8;
    const ushort16_t* bp = xbf + (size_t)col * CC + kh * 8;
    floatx4 acc = {0.f, 0.f, 0.f, 0.f};
    short8 a0 = *(const short8*)ap;
    short8 b0 = *(const short8*)bp;
    #pragma unroll
    for (int k = 1; k < 12; ++k) {
        short8 a1 = *(const short8*)(ap + k * 32);
        short8 b1 = *(const short8*)(bp + k * 32);
        acc = __builtin_amdgcn_mfma_f32_16x16x32_bf16(a0, b0, acc, 0, 0, 0);
        a0 = a1; b0 = b1;
    }
    acc = __builtin_amdgcn_mfma_f32_16x16x32_bf16(a0, b0, acc, 0, 0, 0);
    int b = col >> 10, n = col & 1023;
    #pragma unroll
    for (int r = 0; r < 4; ++r) {
        int ch = r0 + (lane >> 4) * 4 + r;
        qkv[((size_t)b * TOTCH + ch) * NPIX + n] = acc[r];
    }
}

// ---------------- K2: BN stats + softmax (merged, float4) -------------------
__global__ __launch_bounds__(256) void k_bnsm(const float* __restrict__ qkv,
    const float* __restrict__ gq, const float* __restrict__ bq,
    const float* __restrict__ gv, const float* __restrict__ bv,
    float* __restrict__ sA, float* __restrict__ sB, float* __restrict__ ksm)
{
    int bx = blockIdx.x, tid = threadIdx.x;
    int wid = tid >> 6, lane = tid & 63;
    if (bx < 160) {
        int ch = bx;
        int row; float gamma, beta;
        if (ch < 64) { row = ch; gamma = gq[ch]; beta = bq[ch]; }
        else { int j = ch - 64; row = 80 + j; gamma = gv[j]; beta = bv[j]; }
        float s = 0.f, ss = 0.f;
        #pragma unroll
        for (int j = 0; j < 8; ++j) {
            int i4 = tid + 256 * j;
            int b = i4 >> 8, n4 = i4 & 255;
            float4 f = *(const float4*)(qkv + ((size_t)b * TOTCH + row) * NPIX
                                            + n4 * 4);
            s  += f.x + f.y + f.z + f.w;
            ss += f.x * f.x + f.y * f.y + f.z * f.z + f.w * f.w;
        }
        #pragma unroll
        for (int off = 32; off > 0; off >>= 1) {
            s  += __shfl_down(s, off);
            ss += __shfl_down(ss, off);
        }
        __shared__ float rs[4], rss[4];
        if (lane == 0) { rs[wid] = s; rss[wid] = ss; }
        __syncthreads();
        if (tid == 0) {
            float S  = rs[0] + rs[1] + rs[2] + rs[3];
            float SS = rss[0] + rss[1] + rss[2] + rss[3];
            float inv = 1.f / (BB * NPIX);
            float mean = S * inv;
            float var  = SS * inv - mean * mean;
            float a = gamma * rsqrtf(var + BN_EPS);
            sA[row] = a;
            sB[row] = beta - mean * a;
        }
    } else {
        int idx = bx - 160;
        int kc = idx & 15, b = idx >> 4;
        const float* rowp = qkv + ((size_t)b * TOTCH + 64 + kc) * NPIX;
        float4 v4 = *(const float4*)(rowp + tid * 4);
        float v[4] = {v4.x, v4.y, v4.z, v4.w};
        float mx = fmaxf(fmaxf(v[0], v[1]), fmaxf(v[2], v[3]));
        #pragma unroll
        for (int off = 32; off > 0; off >>= 1) mx = fmaxf(mx, __shfl_down(mx, off));
        __shared__ float sm[4], ssum[4];
        if (lane == 0) sm[wid] = mx;
        __syncthreads();
        mx = fmaxf(fmaxf(sm[0], sm[1]), fmaxf(sm[2], sm[3]));
        float e[4], s = 0.f;
        #pragma unroll
        for (int j = 0; j < 4; ++j) { e[j] = __expf(v[j] - mx); s += e[j]; }
        #pragma unroll
        for (int off = 32; off > 0; off >>= 1) s += __shfl_down(s, off);
        if (lane == 0) ssum[wid] = s;
        __syncthreads();
        float inv = 1.f / (ssum[0] + ssum[1] + ssum[2] + ssum[3]);
        float4 o;
        o.x = e[0] * inv; o.y = e[1] * inv; o.z = e[2] * inv; o.w = e[3] * inv;
        *(float4*)(ksm + ((size_t)b * 16 + kc) * NPIX + tid * 4) = o;
    }
}

// ---------------- K3: pack q/v (bf16 tiled) + content lambda (fused) --------
__global__ __launch_bounds__(256) void k_packlc(const float* __restrict__ qkv,
    const float* __restrict__ sA, const float* __restrict__ sB,
    const float* __restrict__ ksm,
    ushort16_t* __restrict__ qt_g, ushort16_t* __restrict__ vt_g,
    ushort16_t* __restrict__ lc_g)
{
    int bx = blockIdx.x, t = threadIdx.x;
    if (bx < 128) {
        // q part: qt_g[n][kh][bh][8]; one (n, bh) per thread
        int bh = t & 31, nn = (t >> 5) & 7;
        int n = bx * 8 + nn;
        int b = bh >> 2, h = bh & 3;
        float vals[16];
        #pragma unroll
        for (int k = 0; k < 16; ++k) {
            int ch = h * 16 + k;
            vals[k] = qkv[((size_t)b * TOTCH + ch) * NPIX + n] * sA[ch] + sB[ch];
        }
        uint4 w0, w1;
        w0.x = pk2(vals[0], vals[1]);  w0.y = pk2(vals[2], vals[3]);
        w0.z = pk2(vals[4], vals[5]);  w0.w = pk2(vals[6], vals[7]);
        w1.x = pk2(vals[8], vals[9]);  w1.y = pk2(vals[10], vals[11]);
        w1.z = pk2(vals[12], vals[13]); w1.w = pk2(vals[14], vals[15]);
        *(uint4*)&qt_g[(size_t)n * 512 + bh * 8]       = w0;
        *(uint4*)&qt_g[(size_t)n * 512 + 256 + bh * 8] = w1;
    } else if (bx < 512) {
        // v part: vt_g[b][mt][vh][vt][mq][vl][8]
        int gi = (bx - 128) * 256 + t;   // < 98304
        int m8 = gi & 127;
        int vg = (gi >> 7) % 96;
        int b  = gi / (96 * 128);
        int m  = m8 * 8;
        int row = 80 + vg;
        float a = sA[row], bb = sB[row];
        const float* p = qkv + ((size_t)b * TOTCH + row) * NPIX + m;
        float4 f0 = *(const float4*)p;
        float4 f1 = *(const float4*)(p + 4);
        uint4 w;
        w.x = pk2(f0.x * a + bb, f0.y * a + bb);
        w.y = pk2(f0.z * a + bb, f0.w * a + bb);
        w.z = pk2(f1.x * a + bb, f1.y * a + bb);
        w.w = pk2(f1.z * a + bb, f1.w * a + bb);
        int mt = m >> 5, mq = (m >> 3) & 3;
        int vhh = vg / 48, vtt = (vg % 48) >> 4, vl = vg & 15;
        size_t idx = ((((size_t)b * 32 + mt) * 2 + vhh) * 3 + vtt) * 512
                   + mq * 128 + vl * 8;
        *(uint4*)&vt_g[idx] = w;
    } else {
        // content lambda: thread t owns m in [4t, 4t+4) -> coalesced rows
        int gi = bx - 512;
        int v = gi % 96, b = gi / 96;
        int row = 80 + v;
        float a = sA[row], bb = sB[row];
        const float* vp = qkv + ((size_t)b * TOTCH + row) * NPIX;
        const float* kp = ksm + (size_t)b * 16 * NPIX;
        float4 vv = *(const float4*)(vp + t * 4);
        float4 vhat;
        vhat.x = vv.x * a + bb; vhat.y = vv.y * a + bb;
        vhat.z = vv.z * a + bb; vhat.w = vv.w * a + bb;
        float acc[16];
        #pragma unroll
        for (int k = 0; k < 16; ++k) {
            float4 kk = *(const float4*)(kp + (size_t)k * NPIX + t * 4);
            acc[k] = kk.x * vhat.x + kk.y * vhat.y
                   + kk.z * vhat.z + kk.w * vhat.w;
        }
        #pragma unroll
        for (int k = 0; k < 16; ++k) {
            #pragma unroll
            for (int off = 32; off > 0; off >>= 1)
                acc[k] += __shfl_down(acc[k], off);
        }
        __shared__ float red[16][4];
        int wid = t >> 6, lane = t & 63;
        if (lane == 0) {
            #pragma unroll
            for (int k = 0; k < 16; ++k) red[k][wid] = acc[k];
        }
        __syncthreads();
        int vhh = v / 48, vtt = (v % 48) >> 4, vl = v & 15;
        size_t plane = ((size_t)(b * 2 + vhh) * 3 + vtt) * 512;
        if (t < 16) {
            int k = t;
            float val = red[k][0] + red[k][1] + red[k][2] + red[k][3];
            lc_g[plane + (k >> 3) * 128 + vl * 8 + (k & 7)] = f2bf(val);
        } else if (t < 18) {
            int mq = 2 + (t - 16);
            uint4 z; z.x = z.y = z.z = z.w = 0u;
            *(uint4*)&lc_g[plane + mq * 128 + vl * 8] = z;
        }
    }
}

// ---------------- K4: fused MFMA lambda, raw-barrier pipeline ---------------
// grid (128 n0, 2 vh), 512 thr (8 waves). LDS = S_s double buffer ONLY.
// All global loads are wave-private register loads (V, A/P); the barrier only
// protects S_s, so we use s_waitcnt(lgkmcnt(0)) + raw s_barrier — global
// loads issued 1-2 iters ahead stay IN FLIGHT across barriers (AITER-style;
// __syncthreads would force vmcnt(0) and drain them every iteration).
__global__ __launch_bounds__(512, 2) void k_main(const float* __restrict__ pos,
    const ushort16_t* __restrict__ qt_g, const ushort16_t* __restrict__ vt_g,
    const ushort16_t* __restrict__ lc_g, float* __restrict__ out)
{
    __shared__ __align__(16) ushort16_t S_s[2][8192];   // 32 KB
    int tid  = threadIdx.x;
    int lane = tid & 63;
    int wave = tid >> 6;          // phase-1: n index; phase-2: b index
    int n0 = blockIdx.x * 8;
    int vh = blockIdx.y;

    int col1 = lane & 31, half = lane >> 5;
    int pb = col1 >> 2, ph = col1 & 3;
    int pplane = pb * 2 + (ph >> 1);
    int pf = pplane & 7;
    int pcb = ph & 1;
    int b2 = wave;

    // q fragment: fixed for whole kernel
    short8 qfr = *(const short8*)(qt_g + (size_t)(n0 + wave) * 512
                                  + half * 256 + col1 * 8);

    floatx4 acc[2][3];
    #pragma unroll
    for (int hg = 0; hg < 2; ++hg)
        #pragma unroll
        for (int vt = 0; vt < 3; ++vt)
            acc[hg][vt] = floatx4{0.f, 0.f, 0.f, 0.f};

    floatx16 z16;
    #pragma unroll
    for (int i = 0; i < 16; ++i) z16[i] = 0.f;

    // A-frag source: P[n=n0+wave][m=col1 + 32*it][k=half*8 ..], fp32
    const float* pA = pos + ((size_t)(n0 + wave) * 1024 + col1) * 16 + half * 8;
    // V source: vt_g[b2][it][vh][vt][...] + lane*8
    const ushort16_t* pV = vt_g + (size_t)b2 * 98304 + (size_t)vh * 1536
                         + lane * 8;

    // prologue: A(0), A(1), V(0)
    float4 a0c = *(const float4*)(pA);
    float4 a1c = *(const float4*)(pA + 4);
    float4 a0n = *(const float4*)(pA + 512);
    float4 a1n = *(const float4*)(pA + 516);
    short8 av0 = *(const short8*)(pV);
    short8 av1 = *(const short8*)(pV + 512);
    short8 av2 = *(const short8*)(pV + 1024);

    for (int i = 0; i < 32; ++i) {
        // prefetch A(i+2) — HBM-latency (~900cyc) hidden over 2 iters
        float4 a0nn, a1nn;
        if (i < 30) {
            const float* p = pA + (size_t)(i + 2) * 512;
            a0nn = *(const float4*)p;
            a1nn = *(const float4*)(p + 4);
        }
        // prefetch V(i+1) — L2-resident (~200cyc), 1 iter ahead
        short8 nv0, nv1, nv2;
        if (i < 31) {
            const ushort16_t* vp = pV + (size_t)(i + 1) * 3072;
            nv0 = *(const short8*)(vp);
            nv1 = *(const short8*)(vp + 512);
            nv2 = *(const short8*)(vp + 1024);
        }
        // phase-1 (n = wave): S = P * q
        {
            uint4 aw;
            aw.x = pk2(a0c.x, a0c.y); aw.y = pk2(a0c.z, a0c.w);
            aw.z = pk2(a1c.x, a1c.y); aw.w = pk2(a1c.z, a1c.w);
            short8 afr = *(short8*)&aw;
            floatx16 d = __builtin_amdgcn_mfma_f32_32x32x16_bf16(
                afr, qfr, z16, 0, 0, 0);
            int nx = wave ^ pf;
            ushort16_t* Sb = S_s[i & 1];
            #pragma unroll
            for (int q = 0; q < 4; ++q) {
                int c = q * 16 + pcb * 8 + nx;
                uint2 wv;
                wv.x = pk2(d[q * 4 + 0], d[q * 4 + 1]);
                wv.y = pk2(d[q * 4 + 2], d[q * 4 + 3]);
                *(uint2*)&Sb[pplane * 512 + c * 8 + half * 4] = wv;
            }
        }
        // LDS-only barrier: drain DS ops, leave global loads in flight
        __builtin_amdgcn_s_waitcnt(LGKM0_ONLY);
        __builtin_amdgcn_s_barrier();
        // phase-2 (b = wave): acc += V * S
        {
            const ushort16_t* Sb = S_s[i & 1];
            #pragma unroll
            for (int hg = 0; hg < 2; ++hg) {
                int p2 = b2 * 2 + hg, f2 = p2 & 7;
                short8 bs = *(const short8*)&Sb[p2 * 512
                    + ((lane >> 4) * 16 + ((lane & 15) ^ f2)) * 8];
                acc[hg][0] = __builtin_amdgcn_mfma_f32_16x16x32_bf16(
                    av0, bs, acc[hg][0], 0, 0, 0);
                acc[hg][1] = __builtin_amdgcn_mfma_f32_16x16x32_bf16(
                    av1, bs, acc[hg][1], 0, 0, 0);
                acc[hg][2] = __builtin_amdgcn_mfma_f32_16x16x32_bf16(
                    av2, bs, acc[hg][2], 0, 0, 0);
            }
        }
        // rotate prefetch registers
        a0c = a0n; a1c = a1n;
        if (i < 30) { a0n = a0nn; a1n = a1nn; }
        if (i < 31) { av0 = nv0; av1 = nv1; av2 = nv2; }
    }

    // ---- content-lambda extension ----
    {
        const ushort16_t* lsrc = lc_g + (size_t)(b2 * 2 + vh) * 1536 + lane * 8;
        short8 lv0 = *(const short8*)(lsrc);
        short8 lv1 = *(const short8*)(lsrc + 512);
        short8 lv2 = *(const short8*)(lsrc + 1024);
        __syncthreads();   // full drain once; S_s[0] safe to overwrite after
        {
            int c = half * 16 + pcb * 8 + (wave ^ pf);
            *(short8*)&S_s[0][pplane * 512 + c * 8] = qfr;
            int zp = tid >> 5, zr = tid & 31;
            int zc = (2 + (zr >> 4)) * 16 + ((zr & 15) ^ (zp & 7));
            uint4 z; z.x = z.y = z.z = z.w = 0u;
            *(uint4*)&S_s[0][zp * 512 + zc * 8] = z;
        }
        __syncthreads();
        #pragma unroll
        for (int hg = 0; hg < 2; ++hg) {
            int p2 = b2 * 2 + hg, f2 = p2 & 7;
            short8 bs = *(const short8*)&S_s[0][p2 * 512
                + ((lane >> 4) * 16 + ((lane & 15) ^ f2)) * 8];
            acc[hg][0] = __builtin_amdgcn_mfma_f32_16x16x32_bf16(
                lv0, bs, acc[hg][0], 0, 0, 0);
            acc[hg][1] = __builtin_amdgcn_mfma_f32_16x16x32_bf16(
                lv1, bs, acc[hg][1], 0, 0, 0);
            acc[hg][2] = __builtin_amdgcn_mfma_f32_16x16x32_bf16(
                lv2, bs, acc[hg][2], 0, 0, 0);
        }
    }

    // ---- epilogue: direct stores (exclusive slice per block) ----
    {
        int cn = lane & 15;
        int nloc = cn & 7;
        #pragma unroll
        for (int hg = 0; hg < 2; ++hg) {
            int h = hg * 2 + (cn >> 3);
            #pragma unroll
            for (int vt = 0; vt < 3; ++vt) {
                #pragma unroll
                for (int r = 0; r < 4; ++r) {
                    int v = vh * 48 + vt * 16 + (lane >> 4) * 4 + r;
                    out[(size_t)(b2 * 384 + h * 96 + v) * 1024 + n0 + nloc]
                        = acc[hg][vt][r];
                }
            }
        }
    }
}

extern "C" void kernel_launch(void* const* d_in, const int* in_sizes, int n_in,
                              void* d_out, int out_size, void* d_ws, size_t ws_size,
                              hipStream_t stream) {
    const float* x   = (const float*)d_in[0];
    const float* Wq  = (const float*)d_in[1];
    const float* Wk  = (const float*)d_in[2];
    const float* Wv  = (const float*)d_in[3];
    const float* gq  = (const float*)d_in[4];
    const float* bq  = (const float*)d_in[5];
    const float* gv  = (const float*)d_in[6];
    const float* bv  = (const float*)d_in[7];
    const float* pos = (const float*)d_in[8];
    float* out = (float*)d_out;
    float* ws  = (float*)d_ws;

    float* qkv = ws;
    float* sA  = ws + 1441792;
    float* sB  = ws + 1441968;
    float* ksm = ws + 1442144;
    ushort16_t* qt_g = (ushort16_t*)(ws + 1573216);
    ushort16_t* vt_g = (ushort16_t*)(ws + 1835360);
    ushort16_t* lc_g = (ushort16_t*)(ws + 2228576);
    ushort16_t* xbf  = (ushort16_t*)(ws + 2240864);
    ushort16_t* wbf  = (ushort16_t*)(ws + 3813728);

    k_xt<<<dim3(260), dim3(256), 0, stream>>>(x, Wq, Wk, Wv, xbf, wbf);
    k_proj<<<dim3(128, 11), dim3(256), 0, stream>>>(xbf, wbf, qkv);
    k_bnsm<<<dim3(288), dim3(256), 0, stream>>>(qkv, gq, bq, gv, bv, sA, sB, ksm);
    k_packlc<<<dim3(1280), dim3(256), 0, stream>>>(qkv, sA, sB, ksm,
                                                   qt_g, vt_g, lc_g);
    k_main<<<dim3(128, 2), dim3(512), 0, stream>>>(pos, qt_g, vt_g, lc_g, out);
}

// Round 8
// 169.474 us; speedup vs baseline: 1.3704x; 1.0580x over previous
//
#include <hip/hip_runtime.h>

typedef __attribute__((ext_vector_type(8))) short short8;
typedef __attribute__((ext_vector_type(16))) float floatx16;
typedef __attribute__((ext_vector_type(4))) float floatx4;
typedef unsigned short ushort16_t;
typedef unsigned int uint32;

#define BB 8
#define CC 384
#define NPIX 1024
#define TOTCH 176      // 64 q + 16 k + 96 v
#define BN_EPS 1e-5f

// ---------- helpers ----------
__device__ __forceinline__ ushort16_t f2bf(float x) {
    uint32 u = __float_as_uint(x);
    u += 0x7FFFu + ((u >> 16) & 1u);
    return (ushort16_t)(u >> 16);
}
__device__ __forceinline__ uint32 pk2(float a, float b) {
    uint32 ua = __float_as_uint(a); ua += 0x7FFFu + ((ua >> 16) & 1u);
    uint32 ub = __float_as_uint(b); ub += 0x7FFFu + ((ub >> 16) & 1u);
    return (ua >> 16) | (ub & 0xFFFF0000u);
}
__device__ __forceinline__ int div48(int x) {   // valid for x < 16384
    return (int)(((unsigned)x * 21846u) >> 20);
}
// lgkmcnt(0), vmcnt unconstrained (63), expcnt unconstrained (7)
#define LGKM0_ONLY 0xC07F

// ws layout (float units):
// qkv  [B][176][N]        @ 0         (1441792)
// sA   [176]              @ 1441792
// sB   [176]              @ 1441968
// ksm  [B][16][N]         @ 1442144   (131072)
// qt_g bf16 [n][kh2][bh32][8]                 @f 1573216 (262144 f)
// vt_g bf16 [b][mt32][vh2][vt3][mq4][v16][8]  @f 1835360 (393216 f)
// lc_g bf16 [b][vh2][vt3][mq4][v16][8]        @f 2228576 (12288 f)
// wbf  bf16 [row192][c384]                    @f 3813728 (36864 f)

// ---------------- K0: W -> bf16 wbf (tiny) ----------------------------------
__global__ __launch_bounds__(256) void k_wt(const float* __restrict__ Wq,
    const float* __restrict__ Wk, const float* __restrict__ Wv,
    ushort16_t* __restrict__ wbf)
{
    int bx = blockIdx.x, t = threadIdx.x;
    #pragma unroll
    for (int jj = 0; jj < 9; ++jj) {
        int idx8 = (bx * 9 + jj) * 256 + t;   // [0, 9216)
        int row = div48(idx8);
        int g   = idx8 - row * 48;
        float4 f0, f1;
        if (row < 176) {
            const float* src;
            if (row < 64)       src = Wq + (size_t)row * CC;
            else if (row < 80)  src = Wk + (size_t)(row - 64) * CC;
            else                src = Wv + (size_t)(row - 80) * CC;
            f0 = *(const float4*)(src + g * 8);
            f1 = *(const float4*)(src + g * 8 + 4);
        } else {
            f0.x = f0.y = f0.z = f0.w = 0.f;
            f1 = f0;
        }
        uint4 w;
        w.x = pk2(f0.x, f0.y); w.y = pk2(f0.z, f0.w);
        w.z = pk2(f1.x, f1.y); w.w = pk2(f1.z, f1.w);
        *(uint4*)&wbf[(size_t)row * CC + g * 8] = w;
    }
}

// ---------------- K1: fused transpose + q/k/v projection (MFMA) -------------
// Block: 32 pixels (cols) x all 384 c staged in LDS (bf16, transposed), then
// each wave does (col-tile of 16) x (row-tile subset) 16x16x32 MFMA GEMM.
// Kills the xbf global round-trip (12.6 MB write + ~67 MB L2 re-read).
__global__ __launch_bounds__(256) void k_proj(const float* __restrict__ x,
    const ushort16_t* __restrict__ wbf, float* __restrict__ qkv)
{
    __shared__ __align__(16) ushort16_t XT[32 * 392];  // 24.5 KB, pad 392
    int bx = blockIdx.x, t = threadIdx.x;
    int b = bx >> 5, nbase = (bx & 31) * 32;
    const float* xb = x + (size_t)b * (CC * NPIX) + nbase;
    #pragma unroll
    for (int j = 0; j < 12; ++j) {
        int idx = t + 256 * j;           // [0, 3072) = 384 c x 8 n-groups
        int c = idx >> 3, ng = idx & 7;
        float4 f = *(const float4*)(xb + (size_t)c * NPIX + ng * 4);
        int col = ng * 4;
        XT[(col + 0) * 392 + c] = f2bf(f.x);
        XT[(col + 1) * 392 + c] = f2bf(f.y);
        XT[(col + 2) * 392 + c] = f2bf(f.z);
        XT[(col + 3) * 392 + c] = f2bf(f.w);
    }
    __syncthreads();

    int wave = t >> 6, lane = t & 63;
    int ct = wave & 1;            // col-tile (16 cols)
    int rs = wave >> 1;           // row-tile parity
    int col1 = lane & 15, kq = lane >> 4;
    const ushort16_t* bbase = &XT[(ct * 16 + col1) * 392 + kq * 8];
    int n = nbase + ct * 16 + col1;

    for (int r = rs; r < 11; r += 2) {
        int r0 = r * 16;
        const ushort16_t* ap = wbf + (size_t)(r0 + col1) * CC + kq * 8;
        floatx4 acc = {0.f, 0.f, 0.f, 0.f};
        short8 a0 = *(const short8*)ap;
        short8 b0 = *(const short8*)bbase;
        #pragma unroll
        for (int k = 1; k < 12; ++k) {
            short8 a1 = *(const short8*)(ap + k * 32);
            short8 b1 = *(const short8*)(bbase + k * 32);
            acc = __builtin_amdgcn_mfma_f32_16x16x32_bf16(a0, b0, acc, 0, 0, 0);
            a0 = a1; b0 = b1;
        }
        acc = __builtin_amdgcn_mfma_f32_16x16x32_bf16(a0, b0, acc, 0, 0, 0);
        #pragma unroll
        for (int rr = 0; rr < 4; ++rr) {
            int ch = r0 + kq * 4 + rr;
            qkv[((size_t)b * TOTCH + ch) * NPIX + n] = acc[rr];
        }
    }
}

// ---------------- K2: BN stats + softmax (merged, float4) -------------------
__global__ __launch_bounds__(256) void k_bnsm(const float* __restrict__ qkv,
    const float* __restrict__ gq, const float* __restrict__ bq,
    const float* __restrict__ gv, const float* __restrict__ bv,
    float* __restrict__ sA, float* __restrict__ sB, float* __restrict__ ksm)
{
    int bx = blockIdx.x, tid = threadIdx.x;
    int wid = tid >> 6, lane = tid & 63;
    if (bx < 160) {
        int ch = bx;
        int row; float gamma, beta;
        if (ch < 64) { row = ch; gamma = gq[ch]; beta = bq[ch]; }
        else { int j = ch - 64; row = 80 + j; gamma = gv[j]; beta = bv[j]; }
        float s = 0.f, ss = 0.f;
        #pragma unroll
        for (int j = 0; j < 8; ++j) {
            int i4 = tid + 256 * j;
            int b = i4 >> 8, n4 = i4 & 255;
            float4 f = *(const float4*)(qkv + ((size_t)b * TOTCH + row) * NPIX
                                            + n4 * 4);
            s  += f.x + f.y + f.z + f.w;
            ss += f.x * f.x + f.y * f.y + f.z * f.z + f.w * f.w;
        }
        #pragma unroll
        for (int off = 32; off > 0; off >>= 1) {
            s  += __shfl_down(s, off);
            ss += __shfl_down(ss, off);
        }
        __shared__ float rs[4], rss[4];
        if (lane == 0) { rs[wid] = s; rss[wid] = ss; }
        __syncthreads();
        if (tid == 0) {
            float S  = rs[0] + rs[1] + rs[2] + rs[3];
            float SS = rss[0] + rss[1] + rss[2] + rss[3];
            float inv = 1.f / (BB * NPIX);
            float mean = S * inv;
            float var  = SS * inv - mean * mean;
            float a = gamma * rsqrtf(var + BN_EPS);
            sA[row] = a;
            sB[row] = beta - mean * a;
        }
    } else {
        int idx = bx - 160;
        int kc = idx & 15, b = idx >> 4;
        const float* rowp = qkv + ((size_t)b * TOTCH + 64 + kc) * NPIX;
        float4 v4 = *(const float4*)(rowp + tid * 4);
        float v[4] = {v4.x, v4.y, v4.z, v4.w};
        float mx = fmaxf(fmaxf(v[0], v[1]), fmaxf(v[2], v[3]));
        #pragma unroll
        for (int off = 32; off > 0; off >>= 1) mx = fmaxf(mx, __shfl_down(mx, off));
        __shared__ float sm[4], ssum[4];
        if (lane == 0) sm[wid] = mx;
        __syncthreads();
        mx = fmaxf(fmaxf(sm[0], sm[1]), fmaxf(sm[2], sm[3]));
        float e[4], s = 0.f;
        #pragma unroll
        for (int j = 0; j < 4; ++j) { e[j] = __expf(v[j] - mx); s += e[j]; }
        #pragma unroll
        for (int off = 32; off > 0; off >>= 1) s += __shfl_down(s, off);
        if (lane == 0) ssum[wid] = s;
        __syncthreads();
        float inv = 1.f / (ssum[0] + ssum[1] + ssum[2] + ssum[3]);
        float4 o;
        o.x = e[0] * inv; o.y = e[1] * inv; o.z = e[2] * inv; o.w = e[3] * inv;
        *(float4*)(ksm + ((size_t)b * 16 + kc) * NPIX + tid * 4) = o;
    }
}

// ---------------- K3: pack q/v (bf16 tiled) + content lambda (fused) --------
__global__ __launch_bounds__(256) void k_packlc(const float* __restrict__ qkv,
    const float* __restrict__ sA, const float* __restrict__ sB,
    const float* __restrict__ ksm,
    ushort16_t* __restrict__ qt_g, ushort16_t* __restrict__ vt_g,
    ushort16_t* __restrict__ lc_g)
{
    int bx = blockIdx.x, t = threadIdx.x;
    if (bx < 128) {
        // q part: qt_g[n][kh][bh][8]; one (n, bh) per thread
        int bh = t & 31, nn = (t >> 5) & 7;
        int n = bx * 8 + nn;
        int b = bh >> 2, h = bh & 3;
        float vals[16];
        #pragma unroll
        for (int k = 0; k < 16; ++k) {
            int ch = h * 16 + k;
            vals[k] = qkv[((size_t)b * TOTCH + ch) * NPIX + n] * sA[ch] + sB[ch];
        }
        uint4 w0, w1;
        w0.x = pk2(vals[0], vals[1]);  w0.y = pk2(vals[2], vals[3]);
        w0.z = pk2(vals[4], vals[5]);  w0.w = pk2(vals[6], vals[7]);
        w1.x = pk2(vals[8], vals[9]);  w1.y = pk2(vals[10], vals[11]);
        w1.z = pk2(vals[12], vals[13]); w1.w = pk2(vals[14], vals[15]);
        *(uint4*)&qt_g[(size_t)n * 512 + bh * 8]       = w0;
        *(uint4*)&qt_g[(size_t)n * 512 + 256 + bh * 8] = w1;
    } else if (bx < 512) {
        // v part: vt_g[b][mt][vh][vt][mq][vl][8]
        int gi = (bx - 128) * 256 + t;   // < 98304
        int m8 = gi & 127;
        int vg = (gi >> 7) % 96;
        int b  = gi / (96 * 128);
        int m  = m8 * 8;
        int row = 80 + vg;
        float a = sA[row], bb = sB[row];
        const float* p = qkv + ((size_t)b * TOTCH + row) * NPIX + m;
        float4 f0 = *(const float4*)p;
        float4 f1 = *(const float4*)(p + 4);
        uint4 w;
        w.x = pk2(f0.x * a + bb, f0.y * a + bb);
        w.y = pk2(f0.z * a + bb, f0.w * a + bb);
        w.z = pk2(f1.x * a + bb, f1.y * a + bb);
        w.w = pk2(f1.z * a + bb, f1.w * a + bb);
        int mt = m >> 5, mq = (m >> 3) & 3;
        int vhh = vg / 48, vtt = (vg % 48) >> 4, vl = vg & 15;
        size_t idx = ((((size_t)b * 32 + mt) * 2 + vhh) * 3 + vtt) * 512
                   + mq * 128 + vl * 8;
        *(uint4*)&vt_g[idx] = w;
    } else {
        // content lambda: thread t owns m in [4t, 4t+4) -> coalesced rows
        int gi = bx - 512;
        int v = gi % 96, b = gi / 96;
        int row = 80 + v;
        float a = sA[row], bb = sB[row];
        const float* vp = qkv + ((size_t)b * TOTCH + row) * NPIX;
        const float* kp = ksm + (size_t)b * 16 * NPIX;
        float4 vv = *(const float4*)(vp + t * 4);
        float4 vhat;
        vhat.x = vv.x * a + bb; vhat.y = vv.y * a + bb;
        vhat.z = vv.z * a + bb; vhat.w = vv.w * a + bb;
        float acc[16];
        #pragma unroll
        for (int k = 0; k < 16; ++k) {
            float4 kk = *(const float4*)(kp + (size_t)k * NPIX + t * 4);
            acc[k] = kk.x * vhat.x + kk.y * vhat.y
                   + kk.z * vhat.z + kk.w * vhat.w;
        }
        #pragma unroll
        for (int k = 0; k < 16; ++k) {
            #pragma unroll
            for (int off = 32; off > 0; off >>= 1)
                acc[k] += __shfl_down(acc[k], off);
        }
        __shared__ float red[16][4];
        int wid = t >> 6, lane = t & 63;
        if (lane == 0) {
            #pragma unroll
            for (int k = 0; k < 16; ++k) red[k][wid] = acc[k];
        }
        __syncthreads();
        int vhh = v / 48, vtt = (v % 48) >> 4, vl = v & 15;
        size_t plane = ((size_t)(b * 2 + vhh) * 3 + vtt) * 512;
        if (t < 16) {
            int k = t;
            float val = red[k][0] + red[k][1] + red[k][2] + red[k][3];
            lc_g[plane + (k >> 3) * 128 + vl * 8 + (k & 7)] = f2bf(val);
        } else if (t < 18) {
            int mq = 2 + (t - 16);
            uint4 z; z.x = z.y = z.z = z.w = 0u;
            *(uint4*)&lc_g[plane + mq * 128 + vl * 8] = z;
        }
    }
}

// ---------------- K4: fused MFMA lambda, raw-barrier pipeline (r7) ----------
__global__ __launch_bounds__(512, 2) void k_main(const float* __restrict__ pos,
    const ushort16_t* __restrict__ qt_g, const ushort16_t* __restrict__ vt_g,
    const ushort16_t* __restrict__ lc_g, float* __restrict__ out)
{
    __shared__ __align__(16) ushort16_t S_s[2][8192];   // 32 KB
    int tid  = threadIdx.x;
    int lane = tid & 63;
    int wave = tid >> 6;          // phase-1: n index; phase-2: b index
    int n0 = blockIdx.x * 8;
    int vh = blockIdx.y;

    int col1 = lane & 31, half = lane >> 5;
    int pb = col1 >> 2, ph = col1 & 3;
    int pplane = pb * 2 + (ph >> 1);
    int pf = pplane & 7;
    int pcb = ph & 1;
    int b2 = wave;

    short8 qfr = *(const short8*)(qt_g + (size_t)(n0 + wave) * 512
                                  + half * 256 + col1 * 8);

    floatx4 acc[2][3];
    #pragma unroll
    for (int hg = 0; hg < 2; ++hg)
        #pragma unroll
        for (int vt = 0; vt < 3; ++vt)
            acc[hg][vt] = floatx4{0.f, 0.f, 0.f, 0.f};

    floatx16 z16;
    #pragma unroll
    for (int i = 0; i < 16; ++i) z16[i] = 0.f;

    const float* pA = pos + ((size_t)(n0 + wave) * 1024 + col1) * 16 + half * 8;
    const ushort16_t* pV = vt_g + (size_t)b2 * 98304 + (size_t)vh * 1536
                         + lane * 8;

    float4 a0c = *(const float4*)(pA);
    float4 a1c = *(const float4*)(pA + 4);
    float4 a0n = *(const float4*)(pA + 512);
    float4 a1n = *(const float4*)(pA + 516);
    short8 av0 = *(const short8*)(pV);
    short8 av1 = *(const short8*)(pV + 512);
    short8 av2 = *(const short8*)(pV + 1024);

    for (int i = 0; i < 32; ++i) {
        float4 a0nn, a1nn;
        if (i < 30) {
            const float* p = pA + (size_t)(i + 2) * 512;
            a0nn = *(const float4*)p;
            a1nn = *(const float4*)(p + 4);
        }
        short8 nv0, nv1, nv2;
        if (i < 31) {
            const ushort16_t* vp = pV + (size_t)(i + 1) * 3072;
            nv0 = *(const short8*)(vp);
            nv1 = *(const short8*)(vp + 512);
            nv2 = *(const short8*)(vp + 1024);
        }
        {
            uint4 aw;
            aw.x = pk2(a0c.x, a0c.y); aw.y = pk2(a0c.z, a0c.w);
            aw.z = pk2(a1c.x, a1c.y); aw.w = pk2(a1c.z, a1c.w);
            short8 afr = *(short8*)&aw;
            floatx16 d = __builtin_amdgcn_mfma_f32_32x32x16_bf16(
                afr, qfr, z16, 0, 0, 0);
            int nx = wave ^ pf;
            ushort16_t* Sb = S_s[i & 1];
            #pragma unroll
            for (int q = 0; q < 4; ++q) {
                int c = q * 16 + pcb * 8 + nx;
                uint2 wv;
                wv.x = pk2(d[q * 4 + 0], d[q * 4 + 1]);
                wv.y = pk2(d[q * 4 + 2], d[q * 4 + 3]);
                *(uint2*)&Sb[pplane * 512 + c * 8 + half * 4] = wv;
            }
        }
        __builtin_amdgcn_s_waitcnt(LGKM0_ONLY);
        __builtin_amdgcn_s_barrier();
        {
            const ushort16_t* Sb = S_s[i & 1];
            #pragma unroll
            for (int hg = 0; hg < 2; ++hg) {
                int p2 = b2 * 2 + hg, f2 = p2 & 7;
                short8 bs = *(const short8*)&Sb[p2 * 512
                    + ((lane >> 4) * 16 + ((lane & 15) ^ f2)) * 8];
                acc[hg][0] = __builtin_amdgcn_mfma_f32_16x16x32_bf16(
                    av0, bs, acc[hg][0], 0, 0, 0);
                acc[hg][1] = __builtin_amdgcn_mfma_f32_16x16x32_bf16(
                    av1, bs, acc[hg][1], 0, 0, 0);
                acc[hg][2] = __builtin_amdgcn_mfma_f32_16x16x32_bf16(
                    av2, bs, acc[hg][2], 0, 0, 0);
            }
        }
        a0c = a0n; a1c = a1n;
        if (i < 30) { a0n = a0nn; a1n = a1nn; }
        if (i < 31) { av0 = nv0; av1 = nv1; av2 = nv2; }
    }

    // ---- content-lambda extension ----
    {
        const ushort16_t* lsrc = lc_g + (size_t)(b2 * 2 + vh) * 1536 + lane * 8;
        short8 lv0 = *(const short8*)(lsrc);
        short8 lv1 = *(const short8*)(lsrc + 512);
        short8 lv2 = *(const short8*)(lsrc + 1024);
        __syncthreads();
        {
            int c = half * 16 + pcb * 8 + (wave ^ pf);
            *(short8*)&S_s[0][pplane * 512 + c * 8] = qfr;
            int zp = tid >> 5, zr = tid & 31;
            int zc = (2 + (zr >> 4)) * 16 + ((zr & 15) ^ (zp & 7));
            uint4 z; z.x = z.y = z.z = z.w = 0u;
            *(uint4*)&S_s[0][zp * 512 + zc * 8] = z;
        }
        __syncthreads();
        #pragma unroll
        for (int hg = 0; hg < 2; ++hg) {
            int p2 = b2 * 2 + hg, f2 = p2 & 7;
            short8 bs = *(const short8*)&S_s[0][p2 * 512
                + ((lane >> 4) * 16 + ((lane & 15) ^ f2)) * 8];
            acc[hg][0] = __builtin_amdgcn_mfma_f32_16x16x32_bf16(
                lv0, bs, acc[hg][0], 0, 0, 0);
            acc[hg][1] = __builtin_amdgcn_mfma_f32_16x16x32_bf16(
                lv1, bs, acc[hg][1], 0, 0, 0);
            acc[hg][2] = __builtin_amdgcn_mfma_f32_16x16x32_bf16(
                lv2, bs, acc[hg][2], 0, 0, 0);
        }
    }

    // ---- epilogue ----
    {
        int cn = lane & 15;
        int nloc = cn & 7;
        #pragma unroll
        for (int hg = 0; hg < 2; ++hg) {
            int h = hg * 2 + (cn >> 3);
            #pragma unroll
            for (int vt = 0; vt < 3; ++vt) {
                #pragma unroll
                for (int r = 0; r < 4; ++r) {
                    int v = vh * 48 + vt * 16 + (lane >> 4) * 4 + r;
                    out[(size_t)(b2 * 384 + h * 96 + v) * 1024 + n0 + nloc]
                        = acc[hg][vt][r];
                }
            }
        }
    }
}

extern "C" void kernel_launch(void* const* d_in, const int* in_sizes, int n_in,
                              void* d_out, int out_size, void* d_ws, size_t ws_size,
                              hipStream_t stream) {
    const float* x   = (const float*)d_in[0];
    const float* Wq  = (const float*)d_in[1];
    const float* Wk  = (const float*)d_in[2];
    const float* Wv  = (const float*)d_in[3];
    const float* gq  = (const float*)d_in[4];
    const float* bq  = (const float*)d_in[5];
    const float* gv  = (const float*)d_in[6];
    const float* bv  = (const float*)d_in[7];
    const float* pos = (const float*)d_in[8];
    float* out = (float*)d_out;
    float* ws  = (float*)d_ws;

    float* qkv = ws;
    float* sA  = ws + 1441792;
    float* sB  = ws + 1441968;
    float* ksm = ws + 1442144;
    ushort16_t* qt_g = (ushort16_t*)(ws + 1573216);
    ushort16_t* vt_g = (ushort16_t*)(ws + 1835360);
    ushort16_t* lc_g = (ushort16_t*)(ws + 2228576);
    ushort16_t* wbf  = (ushort16_t*)(ws + 3813728);

    k_wt<<<dim3(4), dim3(256), 0, stream>>>(Wq, Wk, Wv, wbf);
    k_proj<<<dim3(256), dim3(256), 0, stream>>>(x, wbf, qkv);
    k_bnsm<<<dim3(288), dim3(256), 0, stream>>>(qkv, gq, bq, gv, bv, sA, sB, ksm);
    k_packlc<<<dim3(1280), dim3(256), 0, stream>>>(qkv, sA, sB, ksm,
                                                   qt_g, vt_g, lc_g);
    k_main<<<dim3(128, 2), dim3(512), 0, stream>>>(pos, qt_g, vt_g, lc_g, out);
}